// Round 8
// baseline (131.142 us; speedup 1.0000x reference)
//
#include <hip/hip_runtime.h>
#include <cmath>

// PillarFeatureNet fused: augment(10ch) -> linear(64) -> BN(inference) -> exact GELU -> max over points.
// Key algebra: y[m][o] = f0*A0 + f1*A1 + f2*A2 + f3*A3 + C_pillar  (C-deferred: scan dot only).
// GELU valley-shaped => max_m gelu(y_m) = max(gelu(max y), gelu(min y)): 2 gelus per (n,o).
// Masked points contribute y = b (BN of 0), merged once when num_points < 32.
// points_mean sums ALL 32 raw rows (reference semantics); mask applies only to the matmul.
//
// R8 (R7 post-mortem: fixed 16-blocks over-scanned (24 vs 16.5 pts) + swizzle staging cost ate
//     the unroll win -> synthesize R6+R7 and attack per-wave load-latency):
//   - scan = 8-point immediate-offset blocks, gated by uniform nfull branches, + a guarded
//     partial block reading only valid points: ~6.5 instr/pt, zero movs/addressing/masking.
//   - grid-stride (4096 blocks, 1-2 iters/wave) with NEXT-ITERATION PREFETCH: the next
//     pair-pair's features/num_points/coors loads issue before current compute -> their
//     latency hides under the scan. Weights/BN constants hoisted out of the loop.
//   - kept from R6 (verified best): dual-pair body, DPP mean reduction, C-deferral, rcp
//     means, packed branchless gelu, compiler-only LDS fence (same-wave DS RAW in-order).

typedef float f32x2 __attribute__((ext_vector_type(2)));

__device__ __forceinline__ float max3f(float a, float b, float c) {
    float d;
    asm("v_max3_f32 %0, %1, %2, %3" : "=v"(d) : "v"(a), "v"(b), "v"(c));
    return d;
}
__device__ __forceinline__ float min3f(float a, float b, float c) {
    float d;
    asm("v_min3_f32 %0, %1, %2, %3" : "=v"(d) : "v"(a), "v"(b), "v"(c));
    return d;
}
__device__ __forceinline__ f32x2 pk_fma(f32x2 a, f32x2 b, f32x2 c) {
    f32x2 d;
    asm("v_pk_fma_f32 %0, %1, %2, %3" : "=v"(d) : "v"(a), "v"(b), "v"(c));
    return d;
}
__device__ __forceinline__ f32x2 pk_mul(f32x2 a, f32x2 b) {
    f32x2 d;
    asm("v_pk_mul_f32 %0, %1, %2" : "=v"(d) : "v"(a), "v"(b));
    return d;
}
__device__ __forceinline__ float fast_exp2(float a) {
    float d;
    asm("v_exp_f32 %0, %1" : "=v"(d) : "v"(a));
    return d;
}

// Packed exact-GELU for 2 values (A&S 7.1.26 erf, branchless). |err| ~2e-6 abs.
__device__ __forceinline__ f32x2 gelu2(f32x2 x) {
    const f32x2 c_t    = {0.70710678f, 0.70710678f};
    const f32x2 c_p    = {0.3275911f, 0.3275911f};
    const f32x2 c_one  = {1.0f, 1.0f};
    const f32x2 b1 = {-0.254829592f, -0.254829592f};
    const f32x2 b2 = { 0.284496736f,  0.284496736f};
    const f32x2 b3 = {-1.421413741f, -1.421413741f};
    const f32x2 b4 = { 1.453152027f,  1.453152027f};
    const f32x2 b5 = {-1.061405429f, -1.061405429f};
    const f32x2 c_k = {-1.02013963f, -1.02013963f};   // arg = -t^2*log2(e)

    f32x2 ax = {fabsf(x.x), fabsf(x.y)};
    f32x2 t  = pk_mul(ax, c_t);
    f32x2 u  = pk_fma(t, c_p, c_one);
    f32x2 s  = {__builtin_amdgcn_rcpf(u.x), __builtin_amdgcn_rcpf(u.y)};
    f32x2 poly = pk_fma(b5, s, b4);
    poly = pk_fma(poly, s, b3);
    poly = pk_fma(poly, s, b2);
    poly = pk_fma(poly, s, b1);
    poly = pk_mul(poly, s);
    f32x2 t3  = pk_mul(ax, c_k);
    f32x2 arg = pk_mul(t, t3);
    f32x2 e   = {fast_exp2(arg.x), fast_exp2(arg.y)};
    f32x2 E   = pk_fma(poly, e, c_one);
    f32x2 h   = pk_mul(x, (f32x2){0.5f, 0.5f});
    f32x2 hax = pk_mul(ax, (f32x2){0.5f, 0.5f});
    return pk_fma(hax, E, h);
}

// DPP half-wave sums: returns sum(lanes 0..31) and sum(lanes 32..63). Pure VALU.
template <int CTRL, int ROW_MASK>
__device__ __forceinline__ float dpp_add(float v) {
    int x = __builtin_amdgcn_update_dpp(0, __builtin_bit_cast(int, v), CTRL, ROW_MASK, 0xf, false);
    return v + __builtin_bit_cast(float, x);
}
__device__ __forceinline__ void half_sums(float v, float& sA, float& sB) {
    v = dpp_add<0x111, 0xf>(v);   // row_shr:1
    v = dpp_add<0x112, 0xf>(v);   // row_shr:2
    v = dpp_add<0x114, 0xf>(v);   // row_shr:4
    v = dpp_add<0x118, 0xf>(v);   // row_shr:8  -> lane15/31/47/63 hold 16-lane sums
    v = dpp_add<0x142, 0xa>(v);   // row_bcast:15 into rows 1,3 -> lane31/63 hold 32-lane sums
    sA = __builtin_bit_cast(float, __builtin_amdgcn_readlane(__builtin_bit_cast(int, v), 31));
    sB = __builtin_bit_cast(float, __builtin_amdgcn_readlane(__builtin_bit_cast(int, v), 63));
}

// 8-point straight-line block: immediate-offset broadcast ds_reads, dual minmax chains.
__device__ __forceinline__ void scan8(const float4* b4,
                                      float A0, float A1, float A2, float A3,
                                      float& mx0, float& mn0, float& mx1, float& mn1) {
    float4 t0 = b4[0], t1 = b4[1], t2 = b4[2], t3 = b4[3];
    float4 t4 = b4[4], t5 = b4[5], t6 = b4[6], t7 = b4[7];
    float y0 = fmaf(t0.x, A0, fmaf(t0.y, A1, fmaf(t0.z, A2, t0.w * A3)));
    float y1 = fmaf(t1.x, A0, fmaf(t1.y, A1, fmaf(t1.z, A2, t1.w * A3)));
    float y2 = fmaf(t2.x, A0, fmaf(t2.y, A1, fmaf(t2.z, A2, t2.w * A3)));
    float y3 = fmaf(t3.x, A0, fmaf(t3.y, A1, fmaf(t3.z, A2, t3.w * A3)));
    float y4 = fmaf(t4.x, A0, fmaf(t4.y, A1, fmaf(t4.z, A2, t4.w * A3)));
    float y5 = fmaf(t5.x, A0, fmaf(t5.y, A1, fmaf(t5.z, A2, t5.w * A3)));
    float y6 = fmaf(t6.x, A0, fmaf(t6.y, A1, fmaf(t6.z, A2, t6.w * A3)));
    float y7 = fmaf(t7.x, A0, fmaf(t7.y, A1, fmaf(t7.z, A2, t7.w * A3)));
    mx0 = max3f(mx0, y0, y1); mn0 = min3f(mn0, y0, y1);
    mx1 = max3f(mx1, y2, y3); mn1 = min3f(mn1, y2, y3);
    mx0 = max3f(mx0, y4, y5); mn0 = min3f(mn0, y4, y5);
    mx1 = max3f(mx1, y6, y7); mn1 = min3f(mn1, y6, y7);
}

// Exact-n scan: full 8-blocks via uniform branches + guarded partial block (reads only
// valid points; n is wave-uniform so all guards are scalar branches, no divergence).
__device__ __forceinline__ void scan_pillar(const float4* base, int n,
                                            float A0, float A1, float A2, float A3,
                                            float& dmax, float& dmin) {
    float mx0 = -INFINITY, mn0 = INFINITY, mx1 = -INFINITY, mn1 = INFINITY;
    const int nfull = n >> 3;
    if (nfull > 0) scan8(base,      A0, A1, A2, A3, mx0, mn0, mx1, mn1);
    if (nfull > 1) scan8(base + 8,  A0, A1, A2, A3, mx0, mn0, mx1, mn1);
    if (nfull > 2) scan8(base + 16, A0, A1, A2, A3, mx0, mn0, mx1, mn1);
    if (nfull > 3) scan8(base + 24, A0, A1, A2, A3, mx0, mn0, mx1, mn1);
    const int rem = n & 7;
    if (rem) {
        const float4* br = base + (nfull << 3);
        #pragma unroll
        for (int j = 0; j < 7; ++j) {
            if (j < rem) {
                float4 t = br[j];
                float y = fmaf(t.x, A0, fmaf(t.y, A1, fmaf(t.z, A2, t.w * A3)));
                mx0 = fmaxf(mx0, y);
                mn0 = fminf(mn0, y);
            }
        }
    }
    dmax = fmaxf(mx0, mx1);
    dmin = fminf(mn0, mn1);
}

__global__ __launch_bounds__(256) void pfn_kernel(
    const float* __restrict__ features,   // (N, 32, 4)
    const int*   __restrict__ num_points, // (N,)
    const int*   __restrict__ coors,      // (N, 4)
    const float* __restrict__ W,          // (64, 10)
    const float* __restrict__ gamma,      // (64,)
    const float* __restrict__ beta,       // (64,)
    const float* __restrict__ rmean,      // (64,)
    const float* __restrict__ rvar,       // (64,)
    float*       __restrict__ out,        // (N, 64)
    int nTotal)
{
    __shared__ float4 lds[512];   // 4 waves x 2 pairs x 64 float4 (fixed-extent reads)

    const int lane = threadIdx.x & 63;
    const int wid  = threadIdx.x >> 6;
    const int wv   = blockIdx.x * 4 + wid;
    const int nPairs  = (nTotal + 1) >> 1;
    const int strideP = gridDim.x * 4 * 2;   // pairs advanced per iteration

    int p = wv * 2;
    if (p >= nPairs) return;

    // ---- hoisted channel constants (amortized over all iterations) ----
    const int o = lane;
    const float w0 = W[o*10+0], w1 = W[o*10+1], w2 = W[o*10+2], w3 = W[o*10+3],
                w4 = W[o*10+4], w5 = W[o*10+5], w6 = W[o*10+6], w7 = W[o*10+7],
                w8 = W[o*10+8], w9 = W[o*10+9];
    const float a = gamma[o] / sqrtf(rvar[o] + 1e-3f);
    const float b = fmaf(-rmean[o], a, beta[o]);
    const float A0 = a*(w0+w4+w7), A1 = a*(w1+w5+w8), A2 = a*(w2+w6+w9), A3 = a*w3;

    const float4* fbase = reinterpret_cast<const float4*>(features);
    float4* slot = &lds[wid * 128];

    // ---- prologue: loads for first iteration ----
    int p1 = (p + 1 < nPairs) ? (p + 1) : p;
    float4 f0 = fbase[(size_t)p * 64 + lane];
    float4 f1 = fbase[(size_t)p1 * 64 + lane];
    int iA0 = 2*p;
    int iB0 = (2*p + 1 < nTotal) ? (2*p + 1) : (nTotal - 1);
    int iA1 = 2*p1;
    int iB1 = (2*p1 + 1 < nTotal) ? (2*p1 + 1) : (nTotal - 1);
    int n0A = num_points[iA0], n0B = num_points[iB0];
    int n1A = num_points[iA1], n1B = num_points[iB1];
    int4 c0A = reinterpret_cast<const int4*>(coors)[iA0];
    int4 c0B = reinterpret_cast<const int4*>(coors)[iB0];
    int4 c1A = reinterpret_cast<const int4*>(coors)[iA1];
    int4 c1B = reinterpret_cast<const int4*>(coors)[iB1];

    for (;;) {
        // ---- prefetch next iteration (latency hides under current compute) ----
        const int pn = p + strideP;
        const bool hasNext = pn < nPairs;
        float4 g0, g1;
        int m0A = 0, m0B = 0, m1A = 0, m1B = 0;
        int4 d0A, d0B, d1A, d1B;
        int jA0 = 0, jB0 = 0, jA1 = 0, jB1 = 0;
        if (hasNext) {
            const int pn1 = (pn + 1 < nPairs) ? (pn + 1) : pn;
            g0 = fbase[(size_t)pn * 64 + lane];
            g1 = fbase[(size_t)pn1 * 64 + lane];
            jA0 = 2*pn;
            jB0 = (2*pn + 1 < nTotal) ? (2*pn + 1) : (nTotal - 1);
            jA1 = 2*pn1;
            jB1 = (2*pn1 + 1 < nTotal) ? (2*pn1 + 1) : (nTotal - 1);
            m0A = num_points[jA0]; m0B = num_points[jB0];
            m1A = num_points[jA1]; m1B = num_points[jB1];
            d0A = reinterpret_cast<const int4*>(coors)[jA0];
            d0B = reinterpret_cast<const int4*>(coors)[jB0];
            d1A = reinterpret_cast<const int4*>(coors)[jA1];
            d1B = reinterpret_cast<const int4*>(coors)[jB1];
        }

        // ---- process current: LDS stage ----
        slot[lane]      = f0;
        slot[64 + lane] = f1;

        // DPP half-wave sums from RAW values (reference sums all 32 rows)
        float s0Ax, s0Bx, s0Ay, s0By, s0Az, s0Bz;
        float s1Ax, s1Bx, s1Ay, s1By, s1Az, s1Bz;
        half_sums(f0.x, s0Ax, s0Bx);
        half_sums(f0.y, s0Ay, s0By);
        half_sums(f0.z, s0Az, s0Bz);
        half_sums(f1.x, s1Ax, s1Bx);
        half_sums(f1.y, s1Ay, s1By);
        half_sums(f1.z, s1Az, s1Bz);

        // means via v_rcp (<=1ulp), voxel-center offsets, K, C (x4 pillars)
        const float rc0A = __builtin_amdgcn_rcpf((float)n0A);
        const float rc0B = __builtin_amdgcn_rcpf((float)n0B);
        const float rc1A = __builtin_amdgcn_rcpf((float)n1A);
        const float rc1B = __builtin_amdgcn_rcpf((float)n1B);

        const float K0A = -((s0Ax*rc0A)*w4 + (s0Ay*rc0A)*w5 + (s0Az*rc0A)*w6
                          + fmaf((float)c0A.z, 0.2f, 0.1f)*w7
                          + fmaf((float)c0A.y, 0.2f, -39.9f)*w8
                          + fmaf((float)c0A.x, 4.0f, -1.0f)*w9);
        const float K0B = -((s0Bx*rc0B)*w4 + (s0By*rc0B)*w5 + (s0Bz*rc0B)*w6
                          + fmaf((float)c0B.z, 0.2f, 0.1f)*w7
                          + fmaf((float)c0B.y, 0.2f, -39.9f)*w8
                          + fmaf((float)c0B.x, 4.0f, -1.0f)*w9);
        const float K1A = -((s1Ax*rc1A)*w4 + (s1Ay*rc1A)*w5 + (s1Az*rc1A)*w6
                          + fmaf((float)c1A.z, 0.2f, 0.1f)*w7
                          + fmaf((float)c1A.y, 0.2f, -39.9f)*w8
                          + fmaf((float)c1A.x, 4.0f, -1.0f)*w9);
        const float K1B = -((s1Bx*rc1B)*w4 + (s1By*rc1B)*w5 + (s1Bz*rc1B)*w6
                          + fmaf((float)c1B.z, 0.2f, 0.1f)*w7
                          + fmaf((float)c1B.y, 0.2f, -39.9f)*w8
                          + fmaf((float)c1B.x, 4.0f, -1.0f)*w9);
        const float C0A = fmaf(a, K0A, b), C0B = fmaf(a, K0B, b);
        const float C1A = fmaf(a, K1A, b), C1B = fmaf(a, K1B, b);

        // compiler-only fence: keep scan reads after the LDS writes (same-wave DS RAW is
        // in-order in HW; validated R6).
        asm volatile("" ::: "memory");

        // exact-n scans (C-deferred)
        float d0Amax, d0Amin, d0Bmax, d0Bmin, d1Amax, d1Amin, d1Bmax, d1Bmin;
        scan_pillar(slot,      n0A, A0, A1, A2, A3, d0Amax, d0Amin);
        scan_pillar(slot + 32, n0B, A0, A1, A2, A3, d0Bmax, d0Bmin);
        scan_pillar(slot + 64, n1A, A0, A1, A2, A3, d1Amax, d1Amin);
        scan_pillar(slot + 96, n1B, A0, A1, A2, A3, d1Bmax, d1Bmin);

        float vmax0A = d0Amax + C0A, vmin0A = d0Amin + C0A;
        float vmax0B = d0Bmax + C0B, vmin0B = d0Bmin + C0B;
        float vmax1A = d1Amax + C1A, vmin1A = d1Amin + C1A;
        float vmax1B = d1Bmax + C1B, vmin1B = d1Bmin + C1B;

        if (n0A < 32) { vmax0A = fmaxf(vmax0A, b); vmin0A = fminf(vmin0A, b); }
        if (n0B < 32) { vmax0B = fmaxf(vmax0B, b); vmin0B = fminf(vmin0B, b); }
        if (n1A < 32) { vmax1A = fmaxf(vmax1A, b); vmin1A = fminf(vmin1A, b); }
        if (n1B < 32) { vmax1B = fmaxf(vmax1B, b); vmin1B = fminf(vmin1B, b); }

        // valley property + packed branchless gelu
        const f32x2 g0Ae = gelu2((f32x2){vmax0A, vmin0A});
        const f32x2 g0Be = gelu2((f32x2){vmax0B, vmin0B});
        const f32x2 g1Ae = gelu2((f32x2){vmax1A, vmin1A});
        const f32x2 g1Be = gelu2((f32x2){vmax1B, vmin1B});

        out[(size_t)iA0 * 64 + o] = fmaxf(g0Ae.x, g0Ae.y);
        if (2*p + 1 < nTotal)  out[(size_t)iB0 * 64 + o] = fmaxf(g0Be.x, g0Be.y);
        out[(size_t)iA1 * 64 + o] = fmaxf(g1Ae.x, g1Ae.y);
        if (2*p1 + 1 < nTotal) out[(size_t)iB1 * 64 + o] = fmaxf(g1Be.x, g1Be.y);

        if (!hasNext) break;

        // ---- rotate prefetched state ----
        p  = pn;
        p1 = (pn + 1 < nPairs) ? (pn + 1) : pn;
        f0 = g0; f1 = g1;
        iA0 = jA0; iB0 = jB0; iA1 = jA1; iB1 = jB1;
        n0A = m0A; n0B = m0B; n1A = m1A; n1B = m1B;
        c0A = d0A; c0B = d0B; c1A = d1A; c1B = d1B;
    }
}

extern "C" void kernel_launch(void* const* d_in, const int* in_sizes, int n_in,
                              void* d_out, int out_size, void* d_ws, size_t ws_size,
                              hipStream_t stream) {
    const float* features   = (const float*)d_in[0];
    const int*   num_points = (const int*)  d_in[1];
    const int*   coors      = (const int*)  d_in[2];
    const float* W          = (const float*)d_in[3];
    const float* gamma      = (const float*)d_in[4];
    const float* beta       = (const float*)d_in[5];
    const float* rmean      = (const float*)d_in[6];
    const float* rvar       = (const float*)d_in[7];
    float* out = (float*)d_out;

    const int nTotal = in_sizes[1];  // N pillars

    // 4096 blocks: 16384 waves x 2 pairs/iter, grid-stride -> 1-2 iters/wave.
    // > resident capacity (8192 waves) so the HW backfills (tail balance), while the
    // prefetch pipeline hides the next iteration's load latency.
    const int nPairs = (nTotal + 1) / 2;
    int blocks = 4096;
    const int maxBlocks = (nPairs + 7) / 8;   // at least 1 iter of 2 pairs per wave
    if (blocks > maxBlocks) blocks = maxBlocks;
    if (blocks < 1) blocks = 1;
    pfn_kernel<<<blocks, 256, 0, stream>>>(features, num_points, coors, W,
                                           gamma, beta, rmean, rvar, out, nTotal);
}

// Round 9
// 121.946 us; speedup vs baseline: 1.0754x; 1.0754x over previous
//
#include <hip/hip_runtime.h>
#include <cmath>

// PillarFeatureNet fused: augment(10ch) -> linear(64) -> BN(inference) -> exact GELU -> max over points.
// Key algebra: y[m][o] = f0*A0 + f1*A1 + f2*A2 + f3*A3 + C_pillar  (C-deferred: scan dot only).
// GELU valley-shaped => max_m gelu(y_m) = max(gelu(max y), gelu(min y)): 2 gelus per (n,o).
// Masked points contribute y = b (BN of 0), merged once when num_points < 32.
// points_mean sums ALL 32 raw rows (reference semantics); mask applies only to the matmul.
//
// R9 (R8 post-mortem: prefetch doubled VGPR (36->68), occupancy 58->24.5%, dur 39.6->50us ->
//     REVERT grid/prefetch to R6's verified one-shot dual-pair structure; KEEP only R8's
//     exact-n scan, the untested half):
//   - scan = gated 8-point straight-line blocks (immediate-offset ds_read_b128, no mov
//     rotation / addressing / loop overhead) + guarded partial block reading exactly n
//     points. ~6 instr/pt vs R6's ~10.5.
//   - everything else == R6 (pfn ~39.6us): one-shot dual-pair waves, 2-pairs-per-wave grid,
//     DPP mean reduction, C-deferral, rcp means, packed branchless gelu, compiler-only fence.

typedef float f32x2 __attribute__((ext_vector_type(2)));

__device__ __forceinline__ float max3f(float a, float b, float c) {
    float d;
    asm("v_max3_f32 %0, %1, %2, %3" : "=v"(d) : "v"(a), "v"(b), "v"(c));
    return d;
}
__device__ __forceinline__ float min3f(float a, float b, float c) {
    float d;
    asm("v_min3_f32 %0, %1, %2, %3" : "=v"(d) : "v"(a), "v"(b), "v"(c));
    return d;
}
__device__ __forceinline__ f32x2 pk_fma(f32x2 a, f32x2 b, f32x2 c) {
    f32x2 d;
    asm("v_pk_fma_f32 %0, %1, %2, %3" : "=v"(d) : "v"(a), "v"(b), "v"(c));
    return d;
}
__device__ __forceinline__ f32x2 pk_mul(f32x2 a, f32x2 b) {
    f32x2 d;
    asm("v_pk_mul_f32 %0, %1, %2" : "=v"(d) : "v"(a), "v"(b));
    return d;
}
__device__ __forceinline__ float fast_exp2(float a) {
    float d;
    asm("v_exp_f32 %0, %1" : "=v"(d) : "v"(a));
    return d;
}

// Packed exact-GELU for 2 values (A&S 7.1.26 erf, branchless). |err| ~2e-6 abs.
__device__ __forceinline__ f32x2 gelu2(f32x2 x) {
    const f32x2 c_t    = {0.70710678f, 0.70710678f};
    const f32x2 c_p    = {0.3275911f, 0.3275911f};
    const f32x2 c_one  = {1.0f, 1.0f};
    const f32x2 b1 = {-0.254829592f, -0.254829592f};
    const f32x2 b2 = { 0.284496736f,  0.284496736f};
    const f32x2 b3 = {-1.421413741f, -1.421413741f};
    const f32x2 b4 = { 1.453152027f,  1.453152027f};
    const f32x2 b5 = {-1.061405429f, -1.061405429f};
    const f32x2 c_k = {-1.02013963f, -1.02013963f};   // arg = -t^2*log2(e)

    f32x2 ax = {fabsf(x.x), fabsf(x.y)};
    f32x2 t  = pk_mul(ax, c_t);
    f32x2 u  = pk_fma(t, c_p, c_one);
    f32x2 s  = {__builtin_amdgcn_rcpf(u.x), __builtin_amdgcn_rcpf(u.y)};
    f32x2 poly = pk_fma(b5, s, b4);
    poly = pk_fma(poly, s, b3);
    poly = pk_fma(poly, s, b2);
    poly = pk_fma(poly, s, b1);
    poly = pk_mul(poly, s);
    f32x2 t3  = pk_mul(ax, c_k);
    f32x2 arg = pk_mul(t, t3);
    f32x2 e   = {fast_exp2(arg.x), fast_exp2(arg.y)};
    f32x2 E   = pk_fma(poly, e, c_one);
    f32x2 h   = pk_mul(x, (f32x2){0.5f, 0.5f});
    f32x2 hax = pk_mul(ax, (f32x2){0.5f, 0.5f});
    return pk_fma(hax, E, h);
}

// DPP half-wave sums: returns sum(lanes 0..31) and sum(lanes 32..63). Pure VALU.
template <int CTRL, int ROW_MASK>
__device__ __forceinline__ float dpp_add(float v) {
    int x = __builtin_amdgcn_update_dpp(0, __builtin_bit_cast(int, v), CTRL, ROW_MASK, 0xf, false);
    return v + __builtin_bit_cast(float, x);
}
__device__ __forceinline__ void half_sums(float v, float& sA, float& sB) {
    v = dpp_add<0x111, 0xf>(v);   // row_shr:1
    v = dpp_add<0x112, 0xf>(v);   // row_shr:2
    v = dpp_add<0x114, 0xf>(v);   // row_shr:4
    v = dpp_add<0x118, 0xf>(v);   // row_shr:8  -> lane15/31/47/63 hold 16-lane sums
    v = dpp_add<0x142, 0xa>(v);   // row_bcast:15 into rows 1,3 -> lane31/63 hold 32-lane sums
    sA = __builtin_bit_cast(float, __builtin_amdgcn_readlane(__builtin_bit_cast(int, v), 31));
    sB = __builtin_bit_cast(float, __builtin_amdgcn_readlane(__builtin_bit_cast(int, v), 63));
}

// 8-point straight-line block: immediate-offset broadcast ds_reads, dual minmax chains.
__device__ __forceinline__ void scan8(const float4* b4,
                                      float A0, float A1, float A2, float A3,
                                      float& mx0, float& mn0, float& mx1, float& mn1) {
    float4 t0 = b4[0], t1 = b4[1], t2 = b4[2], t3 = b4[3];
    float4 t4 = b4[4], t5 = b4[5], t6 = b4[6], t7 = b4[7];
    float y0 = fmaf(t0.x, A0, fmaf(t0.y, A1, fmaf(t0.z, A2, t0.w * A3)));
    float y1 = fmaf(t1.x, A0, fmaf(t1.y, A1, fmaf(t1.z, A2, t1.w * A3)));
    float y2 = fmaf(t2.x, A0, fmaf(t2.y, A1, fmaf(t2.z, A2, t2.w * A3)));
    float y3 = fmaf(t3.x, A0, fmaf(t3.y, A1, fmaf(t3.z, A2, t3.w * A3)));
    float y4 = fmaf(t4.x, A0, fmaf(t4.y, A1, fmaf(t4.z, A2, t4.w * A3)));
    float y5 = fmaf(t5.x, A0, fmaf(t5.y, A1, fmaf(t5.z, A2, t5.w * A3)));
    float y6 = fmaf(t6.x, A0, fmaf(t6.y, A1, fmaf(t6.z, A2, t6.w * A3)));
    float y7 = fmaf(t7.x, A0, fmaf(t7.y, A1, fmaf(t7.z, A2, t7.w * A3)));
    mx0 = max3f(mx0, y0, y1); mn0 = min3f(mn0, y0, y1);
    mx1 = max3f(mx1, y2, y3); mn1 = min3f(mn1, y2, y3);
    mx0 = max3f(mx0, y4, y5); mn0 = min3f(mn0, y4, y5);
    mx1 = max3f(mx1, y6, y7); mn1 = min3f(mn1, y6, y7);
}

// Exact-n scan: full 8-blocks via uniform branches + guarded partial block (reads only
// valid points; n is wave-uniform so all guards are scalar branches, no divergence).
__device__ __forceinline__ void scan_pillar(const float4* base, int n,
                                            float A0, float A1, float A2, float A3,
                                            float& dmax, float& dmin) {
    float mx0 = -INFINITY, mn0 = INFINITY, mx1 = -INFINITY, mn1 = INFINITY;
    const int nfull = n >> 3;
    if (nfull > 0) scan8(base,      A0, A1, A2, A3, mx0, mn0, mx1, mn1);
    if (nfull > 1) scan8(base + 8,  A0, A1, A2, A3, mx0, mn0, mx1, mn1);
    if (nfull > 2) scan8(base + 16, A0, A1, A2, A3, mx0, mn0, mx1, mn1);
    if (nfull > 3) scan8(base + 24, A0, A1, A2, A3, mx0, mn0, mx1, mn1);
    const int rem = n & 7;
    if (rem) {
        const float4* br = base + (nfull << 3);
        #pragma unroll
        for (int j = 0; j < 7; ++j) {
            if (j < rem) {
                float4 t = br[j];
                float y = fmaf(t.x, A0, fmaf(t.y, A1, fmaf(t.z, A2, t.w * A3)));
                mx0 = fmaxf(mx0, y);
                mn0 = fminf(mn0, y);
            }
        }
    }
    dmax = fmaxf(mx0, mx1);
    dmin = fminf(mn0, mn1);
}

__global__ __launch_bounds__(256) void pfn_kernel(
    const float* __restrict__ features,   // (N, 32, 4)
    const int*   __restrict__ num_points, // (N,)
    const int*   __restrict__ coors,      // (N, 4)
    const float* __restrict__ W,          // (64, 10)
    const float* __restrict__ gamma,      // (64,)
    const float* __restrict__ beta,       // (64,)
    const float* __restrict__ rmean,      // (64,)
    const float* __restrict__ rvar,       // (64,)
    float*       __restrict__ out,        // (N, 64)
    int nTotal)
{
    __shared__ float4 lds[512];   // 4 waves x 2 pairs x 64 float4 (exact-extent reads)

    const int lane = threadIdx.x & 63;
    const int wid  = threadIdx.x >> 6;
    const int wv   = blockIdx.x * 4 + wid;
    const int nPairs = (nTotal + 1) >> 1;
    const int p0 = wv * 2;
    if (p0 >= nPairs) return;
    const int p1 = (p0 + 1 < nPairs) ? (p0 + 1) : p0;   // clamp: duplicate work, benign

    // ---- issue both 1KB feature loads up front ----
    const float4* fbase = reinterpret_cast<const float4*>(features);
    const float4 f0 = fbase[(size_t)p0 * 64 + lane];
    const float4 f1 = fbase[(size_t)p1 * 64 + lane];

    const int i0A = 2 * p0;
    const bool h0B = (2 * p0 + 1 < nTotal);
    const int i0B = h0B ? (2 * p0 + 1) : (nTotal - 1);
    const int i1A = 2 * p1;
    const bool h1B = (2 * p1 + 1 < nTotal);
    const int i1B = h1B ? (2 * p1 + 1) : (nTotal - 1);

    const int n0A = num_points[i0A], n0B = num_points[i0B];
    const int n1A = num_points[i1A], n1B = num_points[i1B];
    const int4 c0A = reinterpret_cast<const int4*>(coors)[i0A];
    const int4 c0B = reinterpret_cast<const int4*>(coors)[i0B];
    const int4 c1A = reinterpret_cast<const int4*>(coors)[i1A];
    const int4 c1B = reinterpret_cast<const int4*>(coors)[i1B];

    // lane == output channel o
    const int o = lane;
    const float w0 = W[o*10+0], w1 = W[o*10+1], w2 = W[o*10+2], w3 = W[o*10+3],
                w4 = W[o*10+4], w5 = W[o*10+5], w6 = W[o*10+6], w7 = W[o*10+7],
                w8 = W[o*10+8], w9 = W[o*10+9];
    const float a = gamma[o] / sqrtf(rvar[o] + 1e-3f);
    const float b = fmaf(-rmean[o], a, beta[o]);
    const float A0 = a*(w0+w4+w7), A1 = a*(w1+w5+w8), A2 = a*(w2+w6+w9), A3 = a*w3;

    // ---- LDS stage (per-wave 2KB: pair0 at +0, pair1 at +64) ----
    float4* slot = &lds[wid * 128];
    slot[lane]      = f0;
    slot[64 + lane] = f1;

    // ---- DPP half-wave sums (off critical path thanks to C-deferral) ----
    float s0Ax, s0Bx, s0Ay, s0By, s0Az, s0Bz;
    float s1Ax, s1Bx, s1Ay, s1By, s1Az, s1Bz;
    half_sums(f0.x, s0Ax, s0Bx);
    half_sums(f0.y, s0Ay, s0By);
    half_sums(f0.z, s0Az, s0Bz);
    half_sums(f1.x, s1Ax, s1Bx);
    half_sums(f1.y, s1Ay, s1By);
    half_sums(f1.z, s1Az, s1Bz);

    // means via v_rcp (<=1ulp), voxel-center offsets, K, C  (x4 pillars)
    const float rc0A = __builtin_amdgcn_rcpf((float)n0A);
    const float rc0B = __builtin_amdgcn_rcpf((float)n0B);
    const float rc1A = __builtin_amdgcn_rcpf((float)n1A);
    const float rc1B = __builtin_amdgcn_rcpf((float)n1B);

    const float K0A = -((s0Ax*rc0A)*w4 + (s0Ay*rc0A)*w5 + (s0Az*rc0A)*w6
                      + fmaf((float)c0A.z, 0.2f, 0.1f)*w7
                      + fmaf((float)c0A.y, 0.2f, -39.9f)*w8
                      + fmaf((float)c0A.x, 4.0f, -1.0f)*w9);
    const float K0B = -((s0Bx*rc0B)*w4 + (s0By*rc0B)*w5 + (s0Bz*rc0B)*w6
                      + fmaf((float)c0B.z, 0.2f, 0.1f)*w7
                      + fmaf((float)c0B.y, 0.2f, -39.9f)*w8
                      + fmaf((float)c0B.x, 4.0f, -1.0f)*w9);
    const float K1A = -((s1Ax*rc1A)*w4 + (s1Ay*rc1A)*w5 + (s1Az*rc1A)*w6
                      + fmaf((float)c1A.z, 0.2f, 0.1f)*w7
                      + fmaf((float)c1A.y, 0.2f, -39.9f)*w8
                      + fmaf((float)c1A.x, 4.0f, -1.0f)*w9);
    const float K1B = -((s1Bx*rc1B)*w4 + (s1By*rc1B)*w5 + (s1Bz*rc1B)*w6
                      + fmaf((float)c1B.z, 0.2f, 0.1f)*w7
                      + fmaf((float)c1B.y, 0.2f, -39.9f)*w8
                      + fmaf((float)c1B.x, 4.0f, -1.0f)*w9);
    const float C0A = fmaf(a, K0A, b), C0B = fmaf(a, K0B, b);
    const float C1A = fmaf(a, K1A, b), C1B = fmaf(a, K1B, b);

    // compiler-only fence: keep scan reads after the LDS writes (same-wave DS RAW is
    // in-order in HW; validated R6).
    asm volatile("" ::: "memory");

    // ---- exact-n straight-line scans (C-deferred) ----
    float d0Amax, d0Amin, d0Bmax, d0Bmin, d1Amax, d1Amin, d1Bmax, d1Bmin;
    scan_pillar(slot,      n0A, A0, A1, A2, A3, d0Amax, d0Amin);
    scan_pillar(slot + 32, n0B, A0, A1, A2, A3, d0Bmax, d0Bmin);
    scan_pillar(slot + 64, n1A, A0, A1, A2, A3, d1Amax, d1Amin);
    scan_pillar(slot + 96, n1B, A0, A1, A2, A3, d1Bmax, d1Bmin);

    float vmax0A = d0Amax + C0A, vmin0A = d0Amin + C0A;
    float vmax0B = d0Bmax + C0B, vmin0B = d0Bmin + C0B;
    float vmax1A = d1Amax + C1A, vmin1A = d1Amin + C1A;
    float vmax1B = d1Bmax + C1B, vmin1B = d1Bmin + C1B;

    if (n0A < 32) { vmax0A = fmaxf(vmax0A, b); vmin0A = fminf(vmin0A, b); }
    if (n0B < 32) { vmax0B = fmaxf(vmax0B, b); vmin0B = fminf(vmin0B, b); }
    if (n1A < 32) { vmax1A = fmaxf(vmax1A, b); vmin1A = fminf(vmin1A, b); }
    if (n1B < 32) { vmax1B = fmaxf(vmax1B, b); vmin1B = fminf(vmin1B, b); }

    // valley property + packed branchless gelu (4 independent evals: good ILP)
    const f32x2 g0A = gelu2((f32x2){vmax0A, vmin0A});
    const f32x2 g0B = gelu2((f32x2){vmax0B, vmin0B});
    const f32x2 g1A = gelu2((f32x2){vmax1A, vmin1A});
    const f32x2 g1B = gelu2((f32x2){vmax1B, vmin1B});

    out[(size_t)i0A * 64 + o] = fmaxf(g0A.x, g0A.y);
    if (h0B) out[(size_t)i0B * 64 + o] = fmaxf(g0B.x, g0B.y);
    out[(size_t)i1A * 64 + o] = fmaxf(g1A.x, g1A.y);
    if (h1B) out[(size_t)i1B * 64 + o] = fmaxf(g1B.x, g1B.y);
}

extern "C" void kernel_launch(void* const* d_in, const int* in_sizes, int n_in,
                              void* d_out, int out_size, void* d_ws, size_t ws_size,
                              hipStream_t stream) {
    const float* features   = (const float*)d_in[0];
    const int*   num_points = (const int*)  d_in[1];
    const int*   coors      = (const int*)  d_in[2];
    const float* W          = (const float*)d_in[3];
    const float* gamma      = (const float*)d_in[4];
    const float* beta       = (const float*)d_in[5];
    const float* rmean      = (const float*)d_in[6];
    const float* rvar       = (const float*)d_in[7];
    float* out = (float*)d_out;

    const int nTotal = in_sizes[1];  // N pillars

    // 4 waves x 2 consecutive pairs per wave = 8 pairs/block (R6-verified grid)
    const int nPairs = (nTotal + 1) / 2;
    int blocks = (nPairs + 7) / 8;
    if (blocks < 1) blocks = 1;
    pfn_kernel<<<blocks, 256, 0, stream>>>(features, num_points, coors, W,
                                           gamma, beta, rmean, rvar, out, nTotal);
}